// Round 1
// baseline (180.263 us; speedup 1.0000x reference)
//
#include <hip/hip_runtime.h>
#include <hip/hip_bf16.h>
#include <math.h>

#define D_DIM 512
#define TILE  128
#define BK    32

typedef __bf16 bf16x8 __attribute__((ext_vector_type(8)));
typedef float  f32x4  __attribute__((ext_vector_type(4)));
typedef unsigned long long u64;

// ---- helpers ---------------------------------------------------------------

__device__ inline unsigned int fkey(float f) {
    unsigned int u = __float_as_uint(f);
    return (u & 0x80000000u) ? ~u : (u | 0x80000000u);
}

__device__ inline u64 shfl_xor_u64(u64 x, int m) {
    int lo = __shfl_xor((int)(unsigned)(x & 0xFFFFFFFFull), m, 64);
    int hi = __shfl_xor((int)(unsigned)(x >> 32), m, 64);
    return ((u64)(unsigned)hi << 32) | (u64)(unsigned)lo;
}

__device__ inline void async16(__bf16* lds, const __bf16* g) {
    __builtin_amdgcn_global_load_lds(
        (const __attribute__((address_space(1))) void*)g,
        (__attribute__((address_space(3))) void*)lds,
        16, 0, 0);
}

// ---- kernel 1: row L2-normalize, emit bf16 copy + inv_norm, init best ------

__global__ __launch_bounds__(256) void normalize_rows(
        const float* __restrict__ in, __bf16* __restrict__ xb,
        float* __restrict__ inv_norm, u64* __restrict__ best) {
    int row = blockIdx.x;
    int t   = threadIdx.x;
    const float* rp = in + (size_t)row * D_DIM;
    float v0 = rp[t], v1 = rp[t + 256];
    float s = v0 * v0 + v1 * v1;
    #pragma unroll
    for (int m = 32; m >= 1; m >>= 1) s += __shfl_xor(s, m, 64);
    __shared__ float sb[5];
    if ((t & 63) == 0) sb[t >> 6] = s;
    __syncthreads();
    if (t == 0) {
        float tot = sb[0] + sb[1] + sb[2] + sb[3];
        float inv = 1.0f / fmaxf(sqrtf(tot), 1e-8f);
        sb[4] = inv;
        inv_norm[row] = inv;
        best[row] = 0ull;   // smaller than any real packed key
    }
    __syncthreads();
    float inv = sb[4];
    __bf16* op = xb + (size_t)row * D_DIM;
    op[t]       = (__bf16)(v0 * inv);
    op[t + 256] = (__bf16)(v1 * inv);
}

// ---- kernel 2: C = X·Xᵀ (bf16 MFMA), fused per-row argmax (diag masked) ----
// 128x128 tile / block, 4 waves in 2x2, BK=32, global_load_lds width=16.

__global__ __launch_bounds__(256) void gemm_argmax(
        const __bf16* __restrict__ X, u64* __restrict__ best) {
    __shared__ __bf16 As[TILE * BK];
    __shared__ __bf16 Bs[TILE * BK];
    __shared__ u64 mergebuf[TILE * 2];

    const int t    = threadIdx.x;
    const int lane = t & 63;
    const int w    = t >> 6;
    const int wm   = w >> 1, wn = w & 1;
    const int m0   = blockIdx.x * TILE;
    const int n0   = blockIdx.y * TILE;

    // staging map: thread t covers LDS bytes [t*16, t*16+16) == row t/4, col (t%4)*8
    const int rS = t >> 2;
    const int cS = (t & 3) * 8;
    const __bf16* gA = X + (size_t)(m0 + rS) * D_DIM + cS;
    const __bf16* gB = X + (size_t)(n0 + rS) * D_DIM + cS;
    __bf16* lA = As + t * 8;
    __bf16* lB = Bs + t * 8;

    f32x4 acc[4][4];
    #pragma unroll
    for (int mi = 0; mi < 4; mi++)
        #pragma unroll
        for (int ni = 0; ni < 4; ni++)
            acc[mi][ni] = (f32x4){0.f, 0.f, 0.f, 0.f};

    const int qr   = lane & 15;
    const int quad = lane >> 4;

    for (int k0 = 0; k0 < D_DIM; k0 += BK) {
        async16(lA,           gA + k0);
        async16(lA + 64 * BK, gA + (size_t)64 * D_DIM + k0);
        async16(lB,           gB + k0);
        async16(lB + 64 * BK, gB + (size_t)64 * D_DIM + k0);
        __syncthreads();   // drains vmcnt(0) for the async loads

        bf16x8 af[4], bfr[4];
        #pragma unroll
        for (int mi = 0; mi < 4; mi++)
            af[mi] = *(const bf16x8*)(As + (wm * 64 + mi * 16 + qr) * BK + quad * 8);
        #pragma unroll
        for (int ni = 0; ni < 4; ni++)
            bfr[ni] = *(const bf16x8*)(Bs + (wn * 64 + ni * 16 + qr) * BK + quad * 8);
        #pragma unroll
        for (int mi = 0; mi < 4; mi++)
            #pragma unroll
            for (int ni = 0; ni < 4; ni++)
                acc[mi][ni] = __builtin_amdgcn_mfma_f32_16x16x32_bf16(
                    af[mi], bfr[ni], acc[mi][ni], 0, 0, 0);
        __syncthreads();
    }

    // epilogue: per-row max over this tile's 128 cols (diag -> skip),
    // pack (ordered-float || ~col) so u64 max == (max val, min col on tie).
    const int colg_base = n0 + wn * 64 + qr;
    #pragma unroll
    for (int mi = 0; mi < 4; mi++) {
        #pragma unroll
        for (int r = 0; r < 4; r++) {
            const int rowl = wm * 64 + mi * 16 + quad * 4 + r;
            const int rowg = m0 + rowl;
            u64 key = 0ull;
            #pragma unroll
            for (int ni = 0; ni < 4; ni++) {
                int colg = colg_base + ni * 16;
                if (colg == rowg) continue;   // diagonal: self-match masked
                float v = acc[mi][ni][r];
                u64 k = ((u64)fkey(v) << 32) | (u64)(0xFFFFFFFFu - (unsigned)colg);
                key = key > k ? key : k;
            }
            #pragma unroll
            for (int m = 1; m <= 8; m <<= 1) {
                u64 o = shfl_xor_u64(key, m);
                key = key > o ? key : o;
            }
            if (qr == 0) mergebuf[rowl * 2 + wn] = key;
        }
    }
    __syncthreads();
    if (t < TILE) {
        u64 a = mergebuf[t * 2], b = mergebuf[t * 2 + 1];
        u64 k = a > b ? a : b;
        atomicMax(&best[m0 + t], k);
    }
}

// ---- kernel 3: exact fp32 distance to chosen neighbor, log ------------------

__global__ __launch_bounds__(256) void neighbor_dist(
        const float* __restrict__ in, const float* __restrict__ inv_norm,
        const u64* __restrict__ best, float* __restrict__ rowval) {
    int row = blockIdx.x;
    int t   = threadIdx.x;
    u64 k   = best[row];
    int nbr = (int)(0xFFFFFFFFu - (unsigned)(k & 0xFFFFFFFFull));
    float ir  = inv_norm[row];
    float inb = inv_norm[nbr];
    const float* rp = in + (size_t)row * D_DIM;
    const float* np = in + (size_t)nbr * D_DIM;
    float d0 = rp[t] * ir - np[t] * inb + 1e-8f;
    float d1 = rp[t + 256] * ir - np[t + 256] * inb + 1e-8f;
    float s  = d0 * d0 + d1 * d1;
    #pragma unroll
    for (int m = 32; m >= 1; m >>= 1) s += __shfl_xor(s, m, 64);
    __shared__ float sb[4];
    if ((t & 63) == 0) sb[t >> 6] = s;
    __syncthreads();
    if (t == 0) {
        float tot = sb[0] + sb[1] + sb[2] + sb[3];
        rowval[row] = logf(sqrtf(tot) + 1e-8f);
    }
}

// ---- kernel 4: final mean --------------------------------------------------

__global__ __launch_bounds__(256) void final_reduce(
        const float* __restrict__ rowval, float* __restrict__ out, int B) {
    int t = threadIdx.x;
    float s = 0.f;
    for (int i = t; i < B; i += 256) s += rowval[i];
    #pragma unroll
    for (int m = 32; m >= 1; m >>= 1) s += __shfl_xor(s, m, 64);
    __shared__ float sb[4];
    if ((t & 63) == 0) sb[t >> 6] = s;
    __syncthreads();
    if (t == 0) out[0] = -(sb[0] + sb[1] + sb[2] + sb[3]) / (float)B;
}

// ---- launch ----------------------------------------------------------------

extern "C" void kernel_launch(void* const* d_in, const int* in_sizes, int n_in,
                              void* d_out, int out_size, void* d_ws, size_t ws_size,
                              hipStream_t stream) {
    const float* in = (const float*)d_in[0];
    const int B = in_sizes[0] / D_DIM;          // 8192
    const int nt = B / TILE;                    // 64

    char* w = (char*)d_ws;
    __bf16* xb      = (__bf16*)w;                              // B*D*2 bytes
    float*  invn    = (float*)(w + (size_t)B * D_DIM * 2);     // B*4
    u64*    best    = (u64*)(w + (size_t)B * D_DIM * 2 + (size_t)B * 4);
    float*  rowval  = (float*)(w + (size_t)B * D_DIM * 2 + (size_t)B * 4 + (size_t)B * 8);
    float*  out     = (float*)d_out;

    normalize_rows<<<B, 256, 0, stream>>>(in, xb, invn, best);
    gemm_argmax<<<dim3(nt, nt), 256, 0, stream>>>(xb, best);
    neighbor_dist<<<B, 256, 0, stream>>>(in, invn, best, rowval);
    final_reduce<<<1, 256, 0, stream>>>(rowval, out, B);
}

// Round 2
// 153.991 us; speedup vs baseline: 1.1706x; 1.1706x over previous
//
#include <hip/hip_runtime.h>
#include <hip/hip_bf16.h>
#include <math.h>

#define D_DIM 512
#define TILE  128
#define BK    32

typedef __bf16 bf16x8 __attribute__((ext_vector_type(8)));
typedef float  f32x4  __attribute__((ext_vector_type(4)));
typedef unsigned long long u64;

// ---- helpers ---------------------------------------------------------------

__device__ inline unsigned int fkey(float f) {
    unsigned int u = __float_as_uint(f);
    return (u & 0x80000000u) ? ~u : (u | 0x80000000u);
}

__device__ inline u64 shfl_xor_u64(u64 x, int m) {
    int lo = __shfl_xor((int)(unsigned)(x & 0xFFFFFFFFull), m, 64);
    int hi = __shfl_xor((int)(unsigned)(x >> 32), m, 64);
    return ((u64)(unsigned)hi << 32) | (u64)(unsigned)lo;
}

__device__ inline void async16(__bf16* lds, const __bf16* g) {
    __builtin_amdgcn_global_load_lds(
        (const __attribute__((address_space(1))) void*)g,
        (__attribute__((address_space(3))) void*)lds,
        16, 0, 0);
}

// ---- kernel 1: row L2-normalize (1 wave/row), bf16 copy + inv_norm + init --

__global__ __launch_bounds__(256) void normalize_rows(
        const float* __restrict__ in, __bf16* __restrict__ xb,
        float* __restrict__ inv_norm, u64* __restrict__ best) {
    const int row  = blockIdx.x * 4 + (threadIdx.x >> 6);
    const int lane = threadIdx.x & 63;
    const float4* rp = (const float4*)(in + (size_t)row * D_DIM) + lane * 2;
    float4 a = rp[0], b = rp[1];
    float s = a.x*a.x + a.y*a.y + a.z*a.z + a.w*a.w
            + b.x*b.x + b.y*b.y + b.z*b.z + b.w*b.w;
    #pragma unroll
    for (int m = 1; m <= 32; m <<= 1) s += __shfl_xor(s, m, 64);
    float inv = 1.0f / fmaxf(sqrtf(s), 1e-8f);
    if (lane == 0) {
        inv_norm[row] = inv;
        best[row] = 0ull;   // below any real packed key
    }
    bf16x8 o;
    o[0] = (__bf16)(a.x*inv); o[1] = (__bf16)(a.y*inv);
    o[2] = (__bf16)(a.z*inv); o[3] = (__bf16)(a.w*inv);
    o[4] = (__bf16)(b.x*inv); o[5] = (__bf16)(b.y*inv);
    o[6] = (__bf16)(b.z*inv); o[7] = (__bf16)(b.w*inv);
    ((bf16x8*)(xb + (size_t)row * D_DIM))[lane] = o;
}

// ---- kernel 2: triangular C = X·Xᵀ (bf16 MFMA), row+col argmax epilogue ----
// Only tiles bi<=bj are computed; symmetry gives the lower triangle via the
// column-side reduction. XOR-swizzled LDS chunks kill the 4-way bank
// conflicts while staying global_load_lds-compatible (source addr permuted).

__global__ __launch_bounds__(256) void gemm_argmax(
        const __bf16* __restrict__ X, u64* __restrict__ best, int nt) {
    __shared__ __bf16 As[TILE * BK];
    __shared__ __bf16 Bs[TILE * BK];
    __shared__ u64 rmerge[TILE * 2];
    __shared__ u64 cmerge[TILE * 2];

    // triangular decode: block l -> (bi, bj) with bi <= bj
    int l  = blockIdx.x;
    int bj = (int)((sqrtf(8.0f * (float)l + 1.0f) - 1.0f) * 0.5f);
    while (((bj + 1) * (bj + 2)) / 2 <= l) ++bj;
    while ((bj * (bj + 1)) / 2 > l) --bj;
    const int bi = l - (bj * (bj + 1)) / 2;
    const int m0 = bi * TILE;          // row tile
    const int n0 = bj * TILE;          // col tile
    const bool offdiag = (bi != bj);

    const int t    = threadIdx.x;
    const int lane = t & 63;
    const int w    = t >> 6;
    const int wm   = w >> 1, wn = w & 1;

    // staging: thread t fills LDS bytes [t*16, t*16+16) = row t/4, chunk t&3.
    // LDS chunk c holds global chunk c ^ ((row>>2)&3).
    const int rS  = t >> 2;
    const int cSw = ((t & 3) ^ ((rS >> 2) & 3)) * 8;
    const __bf16* gA = X + (size_t)(m0 + rS) * D_DIM + cSw;
    const __bf16* gB = X + (size_t)(n0 + rS) * D_DIM + cSw;
    __bf16* lA = As + t * 8;
    __bf16* lB = Bs + t * 8;

    f32x4 acc[4][4];
    #pragma unroll
    for (int mi = 0; mi < 4; mi++)
        #pragma unroll
        for (int ni = 0; ni < 4; ni++)
            acc[mi][ni] = (f32x4){0.f, 0.f, 0.f, 0.f};

    const int qr   = lane & 15;
    const int quad = lane >> 4;
    const int swz  = (quad ^ (qr >> 2)) * 8;   // de-swizzled fragment chunk

    for (int k0 = 0; k0 < D_DIM; k0 += BK) {
        async16(lA,           gA + k0);
        async16(lA + 64 * BK, gA + (size_t)64 * D_DIM + k0);
        async16(lB,           gB + k0);
        async16(lB + 64 * BK, gB + (size_t)64 * D_DIM + k0);
        __syncthreads();

        bf16x8 af[4], bfr[4];
        #pragma unroll
        for (int mi = 0; mi < 4; mi++)
            af[mi] = *(const bf16x8*)(As + (wm * 64 + mi * 16 + qr) * BK + swz);
        #pragma unroll
        for (int ni = 0; ni < 4; ni++)
            bfr[ni] = *(const bf16x8*)(Bs + (wn * 64 + ni * 16 + qr) * BK + swz);
        #pragma unroll
        for (int mi = 0; mi < 4; mi++)
            #pragma unroll
            for (int ni = 0; ni < 4; ni++)
                acc[mi][ni] = __builtin_amdgcn_mfma_f32_16x16x32_bf16(
                    af[mi], bfr[ni], acc[mi][ni], 0, 0, 0);
        __syncthreads();
    }

    // ---- row-side argmax: best[m0+row] over this tile's 128 cols ----------
    const int colg_base = n0 + wn * 64 + qr;
    #pragma unroll
    for (int mi = 0; mi < 4; mi++) {
        #pragma unroll
        for (int r = 0; r < 4; r++) {
            const int rowl = wm * 64 + mi * 16 + quad * 4 + r;
            const int rowg = m0 + rowl;
            u64 key = 0ull;
            #pragma unroll
            for (int ni = 0; ni < 4; ni++) {
                int colg = colg_base + ni * 16;
                if (colg == rowg) continue;   // diagonal: self-match masked
                float v = acc[mi][ni][r];
                u64 k = ((u64)fkey(v) << 32) | (u64)(0xFFFFFFFFu - (unsigned)colg);
                key = key > k ? key : k;
            }
            #pragma unroll
            for (int m = 1; m <= 8; m <<= 1) {
                u64 o = shfl_xor_u64(key, m);
                key = key > o ? key : o;
            }
            if (qr == 0) rmerge[rowl * 2 + wn] = key;
        }
    }

    // ---- col-side argmax (symmetry): best[n0+col] over this tile's rows ---
    if (offdiag) {
        #pragma unroll
        for (int ni = 0; ni < 4; ni++) {
            u64 key = 0ull;
            #pragma unroll
            for (int mi = 0; mi < 4; mi++) {
                #pragma unroll
                for (int r = 0; r < 4; r++) {
                    int rowg = m0 + wm * 64 + mi * 16 + quad * 4 + r;
                    float v = acc[mi][ni][r];
                    u64 k = ((u64)fkey(v) << 32) | (u64)(0xFFFFFFFFu - (unsigned)rowg);
                    key = key > k ? key : k;
                }
            }
            u64 o = shfl_xor_u64(key, 16); key = key > o ? key : o;
            o     = shfl_xor_u64(key, 32); key = key > o ? key : o;
            if (quad == 0) cmerge[(wn * 64 + ni * 16 + qr) * 2 + wm] = key;
        }
    }
    __syncthreads();
    if (t < TILE) {
        u64 a = rmerge[t * 2], b = rmerge[t * 2 + 1];
        u64 k = a > b ? a : b;
        atomicMax(&best[m0 + t], k);
        if (offdiag) {
            u64 ca = cmerge[t * 2], cb = cmerge[t * 2 + 1];
            u64 ck = ca > cb ? ca : cb;
            atomicMax(&best[n0 + t], ck);
        }
    }
}

// ---- kernel 3: exact fp32 distance to chosen neighbor (1 wave/row) ---------

__global__ __launch_bounds__(256) void neighbor_dist(
        const float* __restrict__ in, const float* __restrict__ inv_norm,
        const u64* __restrict__ best, float* __restrict__ rowval) {
    const int row  = blockIdx.x * 4 + (threadIdx.x >> 6);
    const int lane = threadIdx.x & 63;
    u64 k   = best[row];
    int nbr = (int)(0xFFFFFFFFu - (unsigned)(k & 0xFFFFFFFFull));
    float ir  = inv_norm[row];
    float inb = inv_norm[nbr];
    const float4* rp = (const float4*)(in + (size_t)row * D_DIM) + lane * 2;
    const float4* np = (const float4*)(in + (size_t)nbr * D_DIM) + lane * 2;
    float4 r0 = rp[0], r1 = rp[1], n0 = np[0], n1 = np[1];
    float d0 = r0.x*ir - n0.x*inb + 1e-8f, d1 = r0.y*ir - n0.y*inb + 1e-8f;
    float d2 = r0.z*ir - n0.z*inb + 1e-8f, d3 = r0.w*ir - n0.w*inb + 1e-8f;
    float d4 = r1.x*ir - n1.x*inb + 1e-8f, d5 = r1.y*ir - n1.y*inb + 1e-8f;
    float d6 = r1.z*ir - n1.z*inb + 1e-8f, d7 = r1.w*ir - n1.w*inb + 1e-8f;
    float s = d0*d0 + d1*d1 + d2*d2 + d3*d3 + d4*d4 + d5*d5 + d6*d6 + d7*d7;
    #pragma unroll
    for (int m = 1; m <= 32; m <<= 1) s += __shfl_xor(s, m, 64);
    if (lane == 0) rowval[row] = logf(sqrtf(s) + 1e-8f);
}

// ---- kernel 4: final mean --------------------------------------------------

__global__ __launch_bounds__(256) void final_reduce(
        const float* __restrict__ rowval, float* __restrict__ out, int B) {
    int t = threadIdx.x;
    const float4* rv = (const float4*)rowval;
    float s = 0.f;
    for (int i = t; i < B / 4; i += 256) {
        float4 v = rv[i];
        s += v.x + v.y + v.z + v.w;
    }
    #pragma unroll
    for (int m = 1; m <= 32; m <<= 1) s += __shfl_xor(s, m, 64);
    __shared__ float sb[4];
    if ((t & 63) == 0) sb[t >> 6] = s;
    __syncthreads();
    if (t == 0) out[0] = -(sb[0] + sb[1] + sb[2] + sb[3]) / (float)B;
}

// ---- launch ----------------------------------------------------------------

extern "C" void kernel_launch(void* const* d_in, const int* in_sizes, int n_in,
                              void* d_out, int out_size, void* d_ws, size_t ws_size,
                              hipStream_t stream) {
    const float* in = (const float*)d_in[0];
    const int B  = in_sizes[0] / D_DIM;         // 8192
    const int nt = B / TILE;                    // 64
    const int ntri = nt * (nt + 1) / 2;         // 2080

    char* w = (char*)d_ws;
    __bf16* xb     = (__bf16*)w;                               // B*D*2 bytes
    float*  invn   = (float*)(w + (size_t)B * D_DIM * 2);      // B*4
    u64*    best   = (u64*)(w + (size_t)B * D_DIM * 2 + (size_t)B * 4);
    float*  rowval = (float*)(w + (size_t)B * D_DIM * 2 + (size_t)B * 4 + (size_t)B * 8);
    float*  out    = (float*)d_out;

    normalize_rows<<<B / 4, 256, 0, stream>>>(in, xb, invn, best);
    gemm_argmax<<<ntri, 256, 0, stream>>>(xb, best, nt);
    neighbor_dist<<<B / 4, 256, 0, stream>>>(in, invn, best, rowval);
    final_reduce<<<1, 256, 0, stream>>>(rowval, out, B);
}